// Round 12
// baseline (159.450 us; speedup 1.0000x reference)
//
#include <hip/hip_runtime.h>
#include <float.h>
#include <math.h>

#define NODE_DIM 256
#define HIDDEN   128
#define HEADS    8
#define HEAD_DIM 16
#define NB       768
#define BATCH    2
#define NNODES   (BATCH * NB)
#define SEP      776          // f16 row stride: 388 words, 388%32=4 (2-way, free)

typedef _Float16 f16;
typedef _Float16 h2 __attribute__((ext_vector_type(2)));
union F2H { float f; h2 h; };

// tanh-GELU, exp2-folded: g = u / (1 + exp2(u*(c1' + c3'*u^2)))
__device__ __forceinline__ float gelu_f(float u) {
  float u2 = u * u;
  float e  = __builtin_amdgcn_exp2f(u * fmaf(u2, -0.10294357f, -2.3022090f));
  return u * __builtin_amdgcn_rcpf(1.0f + e);
}

// =============== K1: QKV (blocks 0..383) + compaction (384,385) + P (386) ====
__global__ __launch_bounds__(256) void prep_kernel(
    const float* __restrict__ nf, const float* __restrict__ pos,
    const int* __restrict__ mask,
    const float* __restrict__ Wq, const float* __restrict__ Wk,
    const float* __restrict__ Wv, const float* __restrict__ W1,
    const float* __restrict__ b1, const float* __restrict__ W2,
    const float* __restrict__ b2,
    float* __restrict__ qc, float* __restrict__ kTc, float* __restrict__ vc,
    float* __restrict__ P, float* __restrict__ b2m,
    float* __restrict__ pcx, float* __restrict__ pcy,
    int* __restrict__ vlist, int* __restrict__ mlist, int* __restrict__ cnt) {
  int blk = blockIdx.x, t = threadIdx.x;

  if (blk < NNODES / 4) {
    // ---- QKV for nodes n0..n0+3, local stable-prefix cidx ----
    int n0 = blk * 4;
    int b = n0 / NB;
    int lo = n0 - b * NB;
    __shared__ int accv;
    if (t == 0) accv = 0;
    __syncthreads();
    for (int jb = 0; jb < lo; jb += 256) {
      int j = jb + t;
      int mv = (j < lo) && (mask[b * NB + j] != 0);
      unsigned long long ball = __ballot(mv);
      if ((t & 63) == 0) atomicAdd(&accv, __popcll(ball));
    }
    __syncthreads();
    int cb = accv;
    int m0 = mask[n0] != 0, m1 = mask[n0 + 1] != 0, m2 = mask[n0 + 2] != 0,
        m3 = mask[n0 + 3] != 0;
    int civ[4] = {cb, cb + m0, cb + m0 + m1, cb + m0 + m1 + m2};
    int mv4[4] = {m0, m1, m2, m3};

    const float* x0 = nf + (size_t)(n0 + 0) * NODE_DIM;
    const float* x1 = nf + (size_t)(n0 + 1) * NODE_DIM;
    const float* x2 = nf + (size_t)(n0 + 2) * NODE_DIM;
    const float* x3 = nf + (size_t)(n0 + 3) * NODE_DIM;
    for (int id = t; id < 3 * HIDDEN; id += 256) {
      int m = id >> 7, c = id & 127;
      const float* W = (m == 0) ? Wq : (m == 1) ? Wk : Wv;
      float a0 = 0.f, a1 = 0.f, a2 = 0.f, a3 = 0.f;
      float e0 = 0.f, e1 = 0.f, e2 = 0.f, e3 = 0.f;
#pragma unroll 8
      for (int kk = 0; kk < NODE_DIM; kk += 2) {
        float w0 = W[kk * HIDDEN + c];             // coalesced
        float w1 = W[(kk + 1) * HIDDEN + c];
        a0 = fmaf(x0[kk], w0, a0);  e0 = fmaf(x0[kk + 1], w1, e0);
        a1 = fmaf(x1[kk], w0, a1);  e1 = fmaf(x1[kk + 1], w1, e1);
        a2 = fmaf(x2[kk], w0, a2);  e2 = fmaf(x2[kk + 1], w1, e2);
        a3 = fmaf(x3[kk], w0, a3);  e3 = fmaf(x3[kk + 1], w1, e3);
      }
      float acc[4] = {a0 + e0, a1 + e1, a2 + e2, a3 + e3};
#pragma unroll
      for (int n = 0; n < 4; ++n) {
        if (mv4[n]) {
          int slot = b * NB + civ[n];
          if (m == 0)      qc[(size_t)slot * HIDDEN + c] = acc[n];
          else if (m == 1) kTc[((size_t)b * HIDDEN + c) * NB + civ[n]] = acc[n];
          else             vc[(size_t)slot * HIDDEN + c] = acc[n];
        }
      }
    }
  } else if (blk < NNODES / 4 + 2) {
    // ---- stable (ascending-j) compaction for batch b ----
    int b = blk - NNODES / 4;
    __shared__ int wcnt[4];
    __shared__ int base2[2];
    if (t < 2) base2[t] = 0;
    __syncthreads();
    int lane = t & 63, w = t >> 6;
    for (int iter = 0; iter < NB / 256; ++iter) {
      int j = iter * 256 + t;
      int mv = mask[b * NB + j] != 0;
      unsigned long long ball = __ballot(mv);
      if (lane == 0) wcnt[w] = __popcll(ball);
      __syncthreads();
      int pv = 0;
      for (int i = 0; i < w; ++i) pv += wcnt[i];
      int pin = (lane == 0) ? 0 : __popcll(ball & (~0ull >> (64 - lane)));
      if (mv) {
        int p = base2[0] + pv + pin;
        vlist[b * NB + p] = j;
        pcx[b * NB + p] = pos[(b * NB + j) * 2];
        pcy[b * NB + p] = pos[(b * NB + j) * 2 + 1];
      } else {
        int pm = base2[1] + (w * 64 - pv) + (lane - pin);
        mlist[b * NB + pm] = j;
      }
      __syncthreads();
      if (t == 0) {
        int tot = wcnt[0] + wcnt[1] + wcnt[2] + wcnt[3];
        base2[0] += tot;
        base2[1] += 256 - tot;
      }
      __syncthreads();
    }
    int nv = base2[0];
    if (t == 0) cnt[b] = nv;
    int nvp = (nv + 3) & ~3;              // zero-pad kTc for float4 reads
    if (t < HIDDEN)
      for (int col = nv; col < nvp; ++col)
        kTc[((size_t)b * HIDDEN + t) * NB + col] = 0.0f;
  } else {
    // ---- pack P + b2m. P row (8 f32): {W1x,W1y,W1d,b1} + W2m[0..7] f16 ----
    __shared__ float w2s[HIDDEN * HEADS];
    for (int idx = t; idx < HIDDEN * HEADS; idx += 256) {
      int c = idx >> 3, h = idx & 7;
      float s = 0.0f;
      for (int d = 0; d < HEAD_DIM; ++d) s += W2[c * HIDDEN + h * HEAD_DIM + d];
      w2s[idx] = s * (1.0f / 16.0f);
    }
    if (t < HEADS) {
      float s = 0.0f;
      for (int d = 0; d < HEAD_DIM; ++d) s += b2[t * HEAD_DIM + d];
      b2m[t] = s * (1.0f / 16.0f);
    }
    __syncthreads();
    if (t < HIDDEN) {
      float* Pr = P + t * 8;
      Pr[0] = W1[t];
      Pr[1] = W1[HIDDEN + t];
      Pr[2] = W1[2 * HIDDEN + t];
      Pr[3] = b1[t];
      f16* ph = (f16*)(Pr + 4);
#pragma unroll
      for (int h = 0; h < HEADS; ++h) ph[h] = (f16)w2s[t * 8 + h];
    }
  }
}

// =============== K2: attention + out-proj + LayerNorm, 1 block/(b,ci) ========
__global__ __launch_bounds__(256) void attn_kernel(
    const float* __restrict__ pcx, const float* __restrict__ pcy,
    const int* __restrict__ cnt, const int* __restrict__ vlist,
    const int* __restrict__ mlist, const float* __restrict__ P,
    const float* __restrict__ b2m, const float* __restrict__ qc,
    const float* __restrict__ kTc, const float* __restrict__ vc,
    const float* __restrict__ nf, const float* __restrict__ Wo,
    const float* __restrict__ bo, const float* __restrict__ gamma,
    const float* __restrict__ beta, float* __restrict__ out) {
  int b = blockIdx.x & 1, ci = blockIdx.x >> 1;
  int t = threadIdx.x;
  int nv = cnt[b];
  if (ci >= nv) {                      // masked node -> x==0 -> LN gives beta
    int node = b * NB + mlist[b * NB + (ci - nv)];
    out[(size_t)node * NODE_DIM + t] = beta[t];
    return;
  }
  int node = b * NB + vlist[b * NB + ci];
  int slot = b * NB + ci;

  __shared__ __align__(16) unsigned char smem[17600];
  f16*   sE    = (f16*)smem;                   // [8][SEP]  12416 B
  float* qs    = (float*)(smem + 12416);       // 512 B
  float* partD = (float*)(smem + 12928);       // [8][128]  4096 B
  float* aggL  = (float*)(smem + 17024);       // 512 B
  float* red   = (float*)(smem + 17536);       // 32 B
  float* invs  = (float*)(smem + 17568);       // 32 B

  if (t < HIDDEN) qs[t] = qc[(size_t)slot * HIDDEN + t];
  float pix = pcx[slot], piy = pcy[slot];
  __syncthreads();

  // ---- A: qk dots, float4 over keys (8 heads x 32 lanes) ----
  {
    int h = t >> 5, l = t & 31;
    const float* kb = kTc + ((size_t)b * HIDDEN + h * 16) * NB;
    float qv[16];
#pragma unroll
    for (int r = 0; r < 16; ++r) qv[r] = qs[h * 16 + r];
    float bh = b2m[h];
    int nvp4 = (nv + 3) >> 2;
    for (int j4 = l; j4 < nvp4; j4 += 32) {
      float4 acc = {0.f, 0.f, 0.f, 0.f};
#pragma unroll
      for (int r = 0; r < 16; ++r) {
        float4 kv = ((const float4*)(kb + (size_t)r * NB))[j4];
        acc.x = fmaf(qv[r], kv.x, acc.x);
        acc.y = fmaf(qv[r], kv.y, acc.y);
        acc.z = fmaf(qv[r], kv.z, acc.z);
        acc.w = fmaf(qv[r], kv.w, acc.w);
      }
      sE[h * SEP + 4 * j4 + 0] = (f16)fmaf(acc.x, 0.25f, bh);
      sE[h * SEP + 4 * j4 + 1] = (f16)fmaf(acc.y, 0.25f, bh);
      sE[h * SEP + 4 * j4 + 2] = (f16)fmaf(acc.z, 0.25f, bh);
      sE[h * SEP + 4 * j4 + 3] = (f16)fmaf(acc.w, 0.25f, bh);
    }
  }
  __syncthreads();

  // ---- B: edge-MLP bias; 3 keys/thread fused in ONE c-loop (shared P load) --
  {
    int k0 = t, k1 = t + 256, k2 = t + 512;
    bool v0 = k0 < nv, v1 = k1 < nv, v2 = k2 < nv;
    int s0 = b * NB + (v0 ? k0 : 0);
    int s1 = b * NB + (v1 ? k1 : 0);
    int s2 = b * NB + (v2 ? k2 : 0);
    float ux0, uy0, dd0, ux1, uy1, dd1, ux2, uy2, dd2;
    {
      float dx = pix - pcx[s0], dy = piy - pcy[s0];
      float sq = fmaf(dx, dx, dy * dy);
      dd0 = __builtin_amdgcn_sqrtf(sq + 1e-6f);
      float inv = fminf(__builtin_amdgcn_rsqf(sq), 1e6f);
      ux0 = dx * inv; uy0 = dy * inv;
    }
    {
      float dx = pix - pcx[s1], dy = piy - pcy[s1];
      float sq = fmaf(dx, dx, dy * dy);
      dd1 = __builtin_amdgcn_sqrtf(sq + 1e-6f);
      float inv = fminf(__builtin_amdgcn_rsqf(sq), 1e6f);
      ux1 = dx * inv; uy1 = dy * inv;
    }
    {
      float dx = pix - pcx[s2], dy = piy - pcy[s2];
      float sq = fmaf(dx, dx, dy * dy);
      dd2 = __builtin_amdgcn_sqrtf(sq + 1e-6f);
      float inv = fminf(__builtin_amdgcn_rsqf(sq), 1e6f);
      ux2 = dx * inv; uy2 = dy * inv;
    }
    h2 acc0[4] = {{0,0},{0,0},{0,0},{0,0}};
    h2 acc1[4] = {{0,0},{0,0},{0,0},{0,0}};
    h2 acc2[4] = {{0,0},{0,0},{0,0},{0,0}};
#pragma unroll 4
    for (int c = 0; c < HIDDEN; ++c) {
      const float4* Pc = (const float4*)(P + c * 8);     // uniform -> s_load x8
      float4 p0 = Pc[0], pw = Pc[1];
      float g0 = gelu_f(fmaf(ux0, p0.x, fmaf(uy0, p0.y, fmaf(dd0, p0.z, p0.w))));
      float g1 = gelu_f(fmaf(ux1, p0.x, fmaf(uy1, p0.y, fmaf(dd1, p0.z, p0.w))));
      float g2 = gelu_f(fmaf(ux2, p0.x, fmaf(uy2, p0.y, fmaf(dd2, p0.z, p0.w))));
      f16 h0 = (f16)g0, h1g = (f16)g1, h2g = (f16)g2;
      h2 gg0 = {h0, h0}, gg1 = {h1g, h1g}, gg2 = {h2g, h2g};
      F2H w0, w1, w2, w3;
      w0.f = pw.x; w1.f = pw.y; w2.f = pw.z; w3.f = pw.w;
      acc0[0] += gg0 * w0.h;  acc1[0] += gg1 * w0.h;  acc2[0] += gg2 * w0.h;
      acc0[1] += gg0 * w1.h;  acc1[1] += gg1 * w1.h;  acc2[1] += gg2 * w1.h;
      acc0[2] += gg0 * w2.h;  acc1[2] += gg1 * w2.h;  acc2[2] += gg2 * w2.h;
      acc0[3] += gg0 * w3.h;  acc1[3] += gg1 * w3.h;  acc2[3] += gg2 * w3.h;
    }
    if (v0) {
      f16* row = sE + k0;
#pragma unroll
      for (int p = 0; p < 4; ++p) {
        row[(2*p+0) * SEP] = (f16)(row[(2*p+0) * SEP] + acc0[p].x);
        row[(2*p+1) * SEP] = (f16)(row[(2*p+1) * SEP] + acc0[p].y);
      }
    }
    if (v1) {
      f16* row = sE + k1;
#pragma unroll
      for (int p = 0; p < 4; ++p) {
        row[(2*p+0) * SEP] = (f16)(row[(2*p+0) * SEP] + acc1[p].x);
        row[(2*p+1) * SEP] = (f16)(row[(2*p+1) * SEP] + acc1[p].y);
      }
    }
    if (v2) {
      f16* row = sE + k2;
#pragma unroll
      for (int p = 0; p < 4; ++p) {
        row[(2*p+0) * SEP] = (f16)(row[(2*p+0) * SEP] + acc2[p].x);
        row[(2*p+1) * SEP] = (f16)(row[(2*p+1) * SEP] + acc2[p].y);
      }
    }
  }
  __syncthreads();

  // ---- C: softmax per head (8 groups x 32 lanes) ----
  {
    int h = t >> 5, l = t & 31;
    f16* row = sE + h * SEP;
    float m = -FLT_MAX;
    for (int jj = l; jj < nv; jj += 32) m = fmaxf(m, (float)row[jj]);
    for (int off = 16; off; off >>= 1) m = fmaxf(m, __shfl_down(m, off, 32));
    m = __shfl(m, 0, 32);
    float s = 0.0f;
    for (int jj = l; jj < nv; jj += 32) {
      float e = __expf((float)row[jj] - m);
      row[jj] = (f16)e;
      s += e;
    }
    for (int off = 16; off; off >>= 1) s += __shfl_down(s, off, 32);
    if (l == 0) invs[h] = 1.0f / s;
  }
  __syncthreads();

  // ---- D: weighted V accumulation, float4 channels x 8 key-groups ----
  {
    int o4 = t & 31, g = t >> 5;
    int h = o4 >> 2;
    float4 acc = {0.f, 0.f, 0.f, 0.f};
    for (int jj = g; jj < nv; jj += 8) {
      float w = (float)sE[h * SEP + jj];
      float4 vv = ((const float4*)(vc + ((size_t)(b * NB + jj)) * HIDDEN))[o4];
      acc.x = fmaf(w, vv.x, acc.x);
      acc.y = fmaf(w, vv.y, acc.y);
      acc.z = fmaf(w, vv.z, acc.z);
      acc.w = fmaf(w, vv.w, acc.w);
    }
    ((float4*)(partD + g * HIDDEN + o4 * 4))[0] = acc;
  }
  __syncthreads();
  if (t < HIDDEN) {
    float s = 0.0f;
#pragma unroll
    for (int g = 0; g < 8; ++g) s += partD[g * HIDDEN + t];
    aggL[t] = s * invs[t >> 4];
  }
  __syncthreads();

  // ---- E: out projection + residual + LayerNorm ----
  {
    float y0 = bo[t], y1 = 0.f, y2 = 0.f, y3 = 0.f;
    const float4* a4 = (const float4*)aggL;
#pragma unroll 4
    for (int kg = 0; kg < 32; ++kg) {
      float4 a = a4[kg];                            // ds_read_b128 broadcast
      y0 = fmaf(a.x, Wo[(4 * kg + 0) * NODE_DIM + t], y0);
      y1 = fmaf(a.y, Wo[(4 * kg + 1) * NODE_DIM + t], y1);
      y2 = fmaf(a.z, Wo[(4 * kg + 2) * NODE_DIM + t], y2);
      y3 = fmaf(a.w, Wo[(4 * kg + 3) * NODE_DIM + t], y3);
    }
    float y = (y0 + y1) + (y2 + y3);
    float xv = nf[(size_t)node * NODE_DIM + t] + y;
    float s = xv, s2 = xv * xv;
    for (int off = 32; off; off >>= 1) {
      s += __shfl_down(s, off, 64);
      s2 += __shfl_down(s2, off, 64);
    }
    if ((t & 63) == 0) { red[t >> 6] = s; red[4 + (t >> 6)] = s2; }
    __syncthreads();
    s  = red[0] + red[1] + red[2] + red[3];
    s2 = red[4] + red[5] + red[6] + red[7];
    float mu = s * (1.0f / NODE_DIM);
    float var = fmaxf(s2 * (1.0f / NODE_DIM) - mu * mu, 0.0f);
    out[(size_t)node * NODE_DIM + t] =
        (xv - mu) * rsqrtf(var + 1e-5f) * gamma[t] + beta[t];
  }
}

extern "C" void kernel_launch(void* const* d_in, const int* in_sizes, int n_in,
                              void* d_out, int out_size, void* d_ws, size_t ws_size,
                              hipStream_t stream) {
  const float* nf    = (const float*)d_in[0];
  const float* pos   = (const float*)d_in[1];
  const int*   mask  = (const int*)  d_in[2];
  const float* Wq    = (const float*)d_in[3];
  const float* Wk    = (const float*)d_in[4];
  const float* Wv    = (const float*)d_in[5];
  const float* W1    = (const float*)d_in[6];
  const float* b1    = (const float*)d_in[7];
  const float* W2    = (const float*)d_in[8];
  const float* b2    = (const float*)d_in[9];
  const float* Wo    = (const float*)d_in[10];
  const float* bo    = (const float*)d_in[11];
  const float* gamma = (const float*)d_in[12];
  const float* beta  = (const float*)d_in[13];

  const int QKV = NNODES * HIDDEN;            // 196608

  float* ws   = (float*)d_ws;
  float* qc   = ws;
  float* kTc  = qc + QKV;
  float* vc   = kTc + QKV;
  float* P    = vc + QKV;                     // 128*8 = 1024
  float* b2m  = P + HIDDEN * 8;               // 8
  float* pcx  = b2m + 8;                      // 1536
  float* pcy  = pcx + NNODES;                 // 1536
  int*   vlist= (int*)(pcy + NNODES);         // 1536
  int*   mlist= vlist + NNODES;               // 1536
  int*   cnt  = mlist + NNODES;               // 2

  prep_kernel<<<NNODES / 4 + 3, 256, 0, stream>>>(
      nf, pos, mask, Wq, Wk, Wv, W1, b1, W2, b2,
      qc, kTc, vc, P, b2m, pcx, pcy, vlist, mlist, cnt);
  attn_kernel<<<NNODES, 256, 0, stream>>>(
      pcx, pcy, cnt, vlist, mlist, P, b2m, qc, kTc, vc,
      nf, Wo, bo, gamma, beta, (float*)d_out);
}

// Round 13
// 137.018 us; speedup vs baseline: 1.1637x; 1.1637x over previous
//
#include <hip/hip_runtime.h>
#include <float.h>
#include <math.h>

#define NODE_DIM 256
#define HIDDEN   128
#define HEADS    8
#define HEAD_DIM 16
#define NB       768
#define BATCH    2
#define NNODES   (BATCH * NB)
#define SEP      776          // f16 row stride: 388 words, 388%32=4 (2-way, free)

typedef _Float16 f16;
typedef _Float16 h2 __attribute__((ext_vector_type(2)));
union F2H { float f; h2 h; unsigned u; };
union V4H { float4 f; h2 h[4]; };

// tanh-GELU, exp2-folded: g = u / (1 + exp2(u*(c1' + c3'*u^2)))
__device__ __forceinline__ float gelu_f(float u) {
  float u2 = u * u;
  float e  = __builtin_amdgcn_exp2f(u * fmaf(u2, -0.10294357f, -2.3022090f));
  return u * __builtin_amdgcn_rcpf(1.0f + e);
}

// == K1: QKV (blocks 0..383) + compaction (384,385) + P (386) + WoP (387) =====
__global__ __launch_bounds__(256) void prep_kernel(
    const float* __restrict__ nf, const float* __restrict__ pos,
    const int* __restrict__ mask,
    const float* __restrict__ Wq, const float* __restrict__ Wk,
    const float* __restrict__ Wv, const float* __restrict__ W1,
    const float* __restrict__ b1, const float* __restrict__ W2,
    const float* __restrict__ b2, const float* __restrict__ Wo,
    float* __restrict__ qc, f16* __restrict__ kTcH, f16* __restrict__ vcH,
    unsigned* __restrict__ WoP,
    float* __restrict__ P, float* __restrict__ b2m,
    float* __restrict__ pcx, float* __restrict__ pcy,
    int* __restrict__ vlist, int* __restrict__ mlist, int* __restrict__ cnt) {
  int blk = blockIdx.x, t = threadIdx.x;

  if (blk < NNODES / 4) {
    // ---- QKV for nodes n0..n0+3, local stable-prefix cidx ----
    int n0 = blk * 4;
    int b = n0 / NB;
    int lo = n0 - b * NB;
    __shared__ int accv;
    if (t == 0) accv = 0;
    __syncthreads();
    for (int jb = 0; jb < lo; jb += 256) {
      int j = jb + t;
      int mv = (j < lo) && (mask[b * NB + j] != 0);
      unsigned long long ball = __ballot(mv);
      if ((t & 63) == 0) atomicAdd(&accv, __popcll(ball));
    }
    __syncthreads();
    int cb = accv;
    int m0 = mask[n0] != 0, m1 = mask[n0 + 1] != 0, m2 = mask[n0 + 2] != 0,
        m3 = mask[n0 + 3] != 0;
    int civ[4] = {cb, cb + m0, cb + m0 + m1, cb + m0 + m1 + m2};
    int mv4[4] = {m0, m1, m2, m3};

    const float* x0 = nf + (size_t)(n0 + 0) * NODE_DIM;
    const float* x1 = nf + (size_t)(n0 + 1) * NODE_DIM;
    const float* x2 = nf + (size_t)(n0 + 2) * NODE_DIM;
    const float* x3 = nf + (size_t)(n0 + 3) * NODE_DIM;
    for (int id = t; id < 3 * HIDDEN; id += 256) {
      int m = id >> 7, c = id & 127;
      const float* W = (m == 0) ? Wq : (m == 1) ? Wk : Wv;
      float a0 = 0.f, a1 = 0.f, a2 = 0.f, a3 = 0.f;
      float e0 = 0.f, e1 = 0.f, e2 = 0.f, e3 = 0.f;
#pragma unroll 8
      for (int kk = 0; kk < NODE_DIM; kk += 2) {
        float w0 = W[kk * HIDDEN + c];             // coalesced
        float w1 = W[(kk + 1) * HIDDEN + c];
        a0 = fmaf(x0[kk], w0, a0);  e0 = fmaf(x0[kk + 1], w1, e0);
        a1 = fmaf(x1[kk], w0, a1);  e1 = fmaf(x1[kk + 1], w1, e1);
        a2 = fmaf(x2[kk], w0, a2);  e2 = fmaf(x2[kk + 1], w1, e2);
        a3 = fmaf(x3[kk], w0, a3);  e3 = fmaf(x3[kk + 1], w1, e3);
      }
      float acc[4] = {a0 + e0, a1 + e1, a2 + e2, a3 + e3};
#pragma unroll
      for (int n = 0; n < 4; ++n) {
        if (mv4[n]) {
          int slot = b * NB + civ[n];
          if (m == 0)      qc[(size_t)slot * HIDDEN + c] = acc[n];
          else if (m == 1) kTcH[((size_t)b * HIDDEN + c) * NB + civ[n]] = (f16)acc[n];
          else             vcH[(size_t)slot * HIDDEN + c] = (f16)acc[n];
        }
      }
    }
  } else if (blk < NNODES / 4 + 2) {
    // ---- stable (ascending-j) compaction for batch b ----
    int b = blk - NNODES / 4;
    __shared__ int wcnt[4];
    __shared__ int base2[2];
    if (t < 2) base2[t] = 0;
    __syncthreads();
    int lane = t & 63, w = t >> 6;
    for (int iter = 0; iter < NB / 256; ++iter) {
      int j = iter * 256 + t;
      int mv = mask[b * NB + j] != 0;
      unsigned long long ball = __ballot(mv);
      if (lane == 0) wcnt[w] = __popcll(ball);
      __syncthreads();
      int pv = 0;
      for (int i = 0; i < w; ++i) pv += wcnt[i];
      int pin = (lane == 0) ? 0 : __popcll(ball & (~0ull >> (64 - lane)));
      if (mv) {
        int p = base2[0] + pv + pin;
        vlist[b * NB + p] = j;
        pcx[b * NB + p] = pos[(b * NB + j) * 2];
        pcy[b * NB + p] = pos[(b * NB + j) * 2 + 1];
      } else {
        int pm = base2[1] + (w * 64 - pv) + (lane - pin);
        mlist[b * NB + pm] = j;
      }
      __syncthreads();
      if (t == 0) {
        int tot = wcnt[0] + wcnt[1] + wcnt[2] + wcnt[3];
        base2[0] += tot;
        base2[1] += 256 - tot;
      }
      __syncthreads();
    }
    int nv = base2[0];
    if (t == 0) cnt[b] = nv;
    int nvp8 = (nv + 7) & ~7;             // zero-pad kTcH for f16x8 reads
    if (t < HIDDEN)
      for (int col = nv; col < nvp8; ++col)
        kTcH[((size_t)b * HIDDEN + t) * NB + col] = (f16)0.0f;
  } else if (blk == NNODES / 4 + 2) {
    // ---- pack P + b2m. P row (8 f32): {W1x,W1y,W1d,b1} + W2m[0..7] f16 ----
    __shared__ float w2s[HIDDEN * HEADS];
    for (int idx = t; idx < HIDDEN * HEADS; idx += 256) {
      int c = idx >> 3, h = idx & 7;
      float s = 0.0f;
      for (int d = 0; d < HEAD_DIM; ++d) s += W2[c * HIDDEN + h * HEAD_DIM + d];
      w2s[idx] = s * (1.0f / 16.0f);
    }
    if (t < HEADS) {
      float s = 0.0f;
      for (int d = 0; d < HEAD_DIM; ++d) s += b2[t * HEAD_DIM + d];
      b2m[t] = s * (1.0f / 16.0f);
    }
    __syncthreads();
    if (t < HIDDEN) {
      float* Pr = P + t * 8;
      Pr[0] = W1[t];
      Pr[1] = W1[HIDDEN + t];
      Pr[2] = W1[2 * HIDDEN + t];
      Pr[3] = b1[t];
      f16* ph = (f16*)(Pr + 4);
#pragma unroll
      for (int h = 0; h < HEADS; ++h) ph[h] = (f16)w2s[t * 8 + h];
    }
  } else {
    // ---- pack Wo as f16 row-pairs: WoP[k2*256+t] = {Wo[2k2][t],Wo[2k2+1][t]} -
    for (int k2 = 0; k2 < 64; ++k2) {
      F2H w;
      w.h = (h2){(f16)Wo[(2 * k2) * NODE_DIM + t],
                 (f16)Wo[(2 * k2 + 1) * NODE_DIM + t]};
      WoP[k2 * 256 + t] = w.u;
    }
  }
}

// =============== K2: attention + out-proj + LayerNorm, 1 block/(b,ci) ========
__global__ __launch_bounds__(256) void attn_kernel(
    const float* __restrict__ pcx, const float* __restrict__ pcy,
    const int* __restrict__ cnt, const int* __restrict__ vlist,
    const int* __restrict__ mlist, const float* __restrict__ P,
    const float* __restrict__ b2m, const float* __restrict__ qc,
    const f16* __restrict__ kTcH, const f16* __restrict__ vcH,
    const unsigned* __restrict__ WoP,
    const float* __restrict__ nf, const float* __restrict__ bo,
    const float* __restrict__ gamma, const float* __restrict__ beta,
    float* __restrict__ out) {
  int b = blockIdx.x & 1, ci = blockIdx.x >> 1;
  int t = threadIdx.x;
  int nv = cnt[b];
  if (ci >= nv) {                      // masked node -> x==0 -> LN gives beta
    int node = b * NB + mlist[b * NB + (ci - nv)];
    out[(size_t)node * NODE_DIM + t] = beta[t];
    return;
  }
  int node = b * NB + vlist[b * NB + ci];
  int slot = b * NB + ci;

  __shared__ __align__(16) unsigned char smem[21760];
  f16*   sE    = (f16*)smem;                   // [8][SEP]   12416 B
  float* qs    = (float*)(smem + 12416);       // 512 B
  float* partD = (float*)(smem + 12928);       // [16][128]  8192 B
  float* aggL  = (float*)(smem + 21120);       // 512 B
  float* red   = (float*)(smem + 21632);       // 32 B
  float* invs  = (float*)(smem + 21664);       // 32 B

  if (t < HIDDEN) qs[t] = qc[(size_t)slot * HIDDEN + t];
  float pix = pcx[slot], piy = pcy[slot];
  __syncthreads();

  // ---- A: qk dots, f16x8 keys per iter (8 heads x 32 lanes), pk_fma ----
  {
    int h = t >> 5, l = t & 31;
    const f16* kb = kTcH + ((size_t)b * HIDDEN + h * 16) * NB;
    h2 qp[16];
#pragma unroll
    for (int r = 0; r < 16; ++r) {
      f16 qh = (f16)qs[h * 16 + r];
      qp[r] = (h2){qh, qh};
    }
    h2 sc4 = {(f16)0.25f, (f16)0.25f};
    f16 bhh = (f16)b2m[h];
    h2 bh2 = {bhh, bhh};
    int n8 = (nv + 7) >> 3;
    for (int j8 = l; j8 < n8; j8 += 32) {
      h2 acc[4] = {{0, 0}, {0, 0}, {0, 0}, {0, 0}};
#pragma unroll
      for (int r = 0; r < 16; ++r) {
        V4H kv;
        kv.f = *(const float4*)(kb + (size_t)r * NB + j8 * 8);
        acc[0] += qp[r] * kv.h[0];
        acc[1] += qp[r] * kv.h[1];
        acc[2] += qp[r] * kv.h[2];
        acc[3] += qp[r] * kv.h[3];
      }
      V4H res;
#pragma unroll
      for (int p = 0; p < 4; ++p) res.h[p] = acc[p] * sc4 + bh2;
      *(float4*)(sE + h * SEP + j8 * 8) = res.f;
    }
  }
  __syncthreads();

  // ---- B: edge-MLP bias; guarded per-slot passes (R11 structure) ----
#pragma unroll
  for (int sl = 0; sl < 3; ++sl) {
    int k0 = t + sl * 256;
    if (k0 < nv) {
      int s0 = b * NB + k0;
      float dx = pix - pcx[s0], dy = piy - pcy[s0];
      float sq = fmaf(dx, dx, dy * dy);
      float dist = __builtin_amdgcn_sqrtf(sq + 1e-6f);
      float inv  = fminf(__builtin_amdgcn_rsqf(sq), 1e6f);
      float ux = dx * inv, uy = dy * inv;
      h2 bacc[4] = {{0, 0}, {0, 0}, {0, 0}, {0, 0}};
#pragma unroll 4
      for (int c = 0; c < HIDDEN; ++c) {
        const float4* Pc = (const float4*)(P + c * 8);   // uniform -> s_load
        float4 p0 = Pc[0], pw = Pc[1];
        float g = gelu_f(fmaf(ux, p0.x, fmaf(uy, p0.y, fmaf(dist, p0.z, p0.w))));
        f16 gh = (f16)g;
        h2 gg = {gh, gh};
        F2H w0, w1, w2, w3;
        w0.f = pw.x; w1.f = pw.y; w2.f = pw.z; w3.f = pw.w;
        bacc[0] += gg * w0.h;
        bacc[1] += gg * w1.h;
        bacc[2] += gg * w2.h;
        bacc[3] += gg * w3.h;
      }
      f16* row = sE + k0;
#pragma unroll
      for (int p = 0; p < 4; ++p) {
        row[(2 * p + 0) * SEP] = (f16)(row[(2 * p + 0) * SEP] + bacc[p].x);
        row[(2 * p + 1) * SEP] = (f16)(row[(2 * p + 1) * SEP] + bacc[p].y);
      }
    }
  }
  __syncthreads();

  // ---- C: softmax per head (8 groups x 32 lanes) ----
  {
    int h = t >> 5, l = t & 31;
    f16* row = sE + h * SEP;
    float m = -FLT_MAX;
    for (int jj = l; jj < nv; jj += 32) m = fmaxf(m, (float)row[jj]);
    for (int off = 16; off; off >>= 1) m = fmaxf(m, __shfl_down(m, off, 32));
    m = __shfl(m, 0, 32);
    float s = 0.0f;
    for (int jj = l; jj < nv; jj += 32) {
      float e = __expf((float)row[jj] - m);
      row[jj] = (f16)e;
      s += e;
    }
    for (int off = 16; off; off >>= 1) s += __shfl_down(s, off, 32);
    if (l == 0) invs[h] = 1.0f / s;
  }
  __syncthreads();

  // ---- D: weighted V, f16x8 channels x 16 key-groups, pk_fma ----
  {
    int o8 = t & 15, g = t >> 4;       // 16 channel-groups x 16 key-groups
    int h = o8 >> 1;
    h2 acc[4] = {{0, 0}, {0, 0}, {0, 0}, {0, 0}};
    for (int jj = g; jj < nv; jj += 16) {
      V4H vv;
      vv.f = *(const float4*)(vcH + (size_t)(b * NB + jj) * HIDDEN + o8 * 8);
      f16 w = sE[h * SEP + jj];
      h2 ww = {w, w};
      acc[0] += ww * vv.h[0];
      acc[1] += ww * vv.h[1];
      acc[2] += ww * vv.h[2];
      acc[3] += ww * vv.h[3];
    }
    float* pd = partD + g * HIDDEN + o8 * 8;
    pd[0] = (float)acc[0].x; pd[1] = (float)acc[0].y;
    pd[2] = (float)acc[1].x; pd[3] = (float)acc[1].y;
    pd[4] = (float)acc[2].x; pd[5] = (float)acc[2].y;
    pd[6] = (float)acc[3].x; pd[7] = (float)acc[3].y;
  }
  __syncthreads();
  if (t < HIDDEN) {
    float s = 0.0f;
#pragma unroll
    for (int g = 0; g < 16; ++g) s += partD[g * HIDDEN + t];
    aggL[t] = s * invs[t >> 4];
  }
  __syncthreads();

  // ---- E: out projection (f16 packed row-pairs) + residual + LayerNorm ----
  {
    float y0 = bo[t], y1 = 0.f;
    const unsigned* wp = WoP + t;
    const float2* a2 = (const float2*)aggL;
#pragma unroll 4
    for (int k2 = 0; k2 < 64; ++k2) {
      F2H w;
      w.u = wp[(size_t)k2 * 256];                 // coalesced 4B
      float2 a = a2[k2];                          // ds_read_b64 broadcast
      y0 = fmaf(a.x, (float)w.h.x, y0);
      y1 = fmaf(a.y, (float)w.h.y, y1);
    }
    float y = y0 + y1;
    float xv = nf[(size_t)node * NODE_DIM + t] + y;
    float s = xv, s2 = xv * xv;
    for (int off = 32; off; off >>= 1) {
      s += __shfl_down(s, off, 64);
      s2 += __shfl_down(s2, off, 64);
    }
    if ((t & 63) == 0) { red[t >> 6] = s; red[4 + (t >> 6)] = s2; }
    __syncthreads();
    s  = red[0] + red[1] + red[2] + red[3];
    s2 = red[4] + red[5] + red[6] + red[7];
    float mu = s * (1.0f / NODE_DIM);
    float var = fmaxf(s2 * (1.0f / NODE_DIM) - mu * mu, 0.0f);
    out[(size_t)node * NODE_DIM + t] =
        (xv - mu) * rsqrtf(var + 1e-5f) * gamma[t] + beta[t];
  }
}

extern "C" void kernel_launch(void* const* d_in, const int* in_sizes, int n_in,
                              void* d_out, int out_size, void* d_ws, size_t ws_size,
                              hipStream_t stream) {
  const float* nf    = (const float*)d_in[0];
  const float* pos   = (const float*)d_in[1];
  const int*   mask  = (const int*)  d_in[2];
  const float* Wq    = (const float*)d_in[3];
  const float* Wk    = (const float*)d_in[4];
  const float* Wv    = (const float*)d_in[5];
  const float* W1    = (const float*)d_in[6];
  const float* b1    = (const float*)d_in[7];
  const float* W2    = (const float*)d_in[8];
  const float* b2    = (const float*)d_in[9];
  const float* Wo    = (const float*)d_in[10];
  const float* bo    = (const float*)d_in[11];
  const float* gamma = (const float*)d_in[12];
  const float* beta  = (const float*)d_in[13];

  const int QKV = NNODES * HIDDEN;            // 196608

  float*    ws   = (float*)d_ws;
  float*    qc   = ws;                        // 196608 f32
  f16*      kTcH = (f16*)(qc + QKV);          // 196608 f16 = 98304 f32
  f16*      vcH  = kTcH + QKV;                // 196608 f16
  unsigned* WoP  = (unsigned*)(vcH + QKV);    // 16384 u32
  float*    P    = (float*)(WoP + 64 * 256);  // 1024
  float*    b2m  = P + HIDDEN * 8;            // 8
  float*    pcx  = b2m + 8;                   // 1536
  float*    pcy  = pcx + NNODES;              // 1536
  int*      vlist= (int*)(pcy + NNODES);      // 1536
  int*      mlist= vlist + NNODES;            // 1536
  int*      cnt  = mlist + NNODES;            // 2

  prep_kernel<<<NNODES / 4 + 4, 256, 0, stream>>>(
      nf, pos, mask, Wq, Wk, Wv, W1, b1, W2, b2, Wo,
      qc, kTcH, vcH, WoP, P, b2m, pcx, pcy, vlist, mlist, cnt);
  attn_kernel<<<NNODES, 256, 0, stream>>>(
      pcx, pcy, cnt, vlist, mlist, P, b2m, qc, kTcH, vcH, WoP,
      nf, bo, gamma, beta, (float*)d_out);
}